// Round 6
// baseline (643.952 us; speedup 1.0000x reference)
//
#include <hip/hip_runtime.h>
#include <cstdint>
#include <cstddef>

// ============================================================================
// ViT block: LN1 -> (QKV + LoRA) -> 14x14 windowed attention (decomposed
// rel-pos bias) -> proj + residual -> LN2 -> MLP (fast-tanh GELU) + residual.
// bf16 MFMA 16x16x32, fp32 acc, BK=64, band-swizzled grid, XOR-swizzled LDS
// (bank-conflict-free fragment reads), non-temporal epilogue stores.
// qkv buffer layout: slot(bw,which,h) stride 13312 elements.
//   Q,K: [tok(208 pad)][64]   V: [64][tok(208 pad)]  (pre-transposed)
// ============================================================================

typedef __bf16 bf16x8 __attribute__((ext_vector_type(8)));
typedef float f32x4 __attribute__((ext_vector_type(4)));

__device__ __forceinline__ unsigned short f2bf(float f) {
    unsigned u = __float_as_uint(f);
    u = (u + 0x7fffu + ((u >> 16) & 1u)) >> 16;
    return (unsigned short)u;
}
__device__ __forceinline__ float bf2f(unsigned short h) {
    return __uint_as_float(((unsigned)h) << 16);
}

// async global->LDS, 16B per lane. LDS layout must be uniform_base + lane*16.
#define GLDS16(gp, lp) __builtin_amdgcn_global_load_lds( \
    (__attribute__((address_space(1))) unsigned int*)(gp), \
    (__attribute__((address_space(3))) unsigned int*)(lp), 16, 0, 0)

// ---------------------------------------------------------------------------
// Weight prep: W_effT[n][k] = qkv_w[k][n] + 2 * sum_r lora_a[k][r]*lora_b[r][n]
// ---------------------------------------------------------------------------
__global__ __launch_bounds__(256) void weff_kernel(
    const float* __restrict__ W, const float* __restrict__ la,
    const float* __restrict__ lb, unsigned short* __restrict__ Wt)
{
    __shared__ float tile[32][33];
    __shared__ float lat[32][16];
    __shared__ float lbt[16][32];
    const int kb = blockIdx.x * 32, nb = blockIdx.y * 32;
    const int tn = threadIdx.x & 31, tk = threadIdx.x >> 5;
    for (int i = threadIdx.x; i < 32 * 16; i += 256)
        lat[i >> 4][i & 15] = la[(size_t)(kb + (i >> 4)) * 16 + (i & 15)];
    for (int i = threadIdx.x; i < 16 * 32; i += 256)
        lbt[i >> 5][i & 31] = lb[(size_t)(i >> 5) * 3072 + nb + (i & 31)];
#pragma unroll
    for (int i = 0; i < 4; ++i) {
        int k = tk + i * 8;
        tile[k][tn] = W[(size_t)(kb + k) * 3072 + nb + tn];
    }
    __syncthreads();
#pragma unroll
    for (int i = 0; i < 4; ++i) {
        int n = tk + i * 8;
        float acc = tile[tn][n];
#pragma unroll
        for (int r = 0; r < 16; ++r) acc += 2.0f * lat[tn][r] * lbt[r][n];
        Wt[(size_t)(nb + n) * 1024 + kb + tn] = f2bf(acc);
    }
}

// fp32 (K x N) -> bf16 transposed (N x K)
__global__ __launch_bounds__(256) void transpose_bf16_kernel(
    const float* __restrict__ W, unsigned short* __restrict__ Wt,
    int Kdim, int Ndim)
{
    __shared__ float tile[32][33];
    const int kb = blockIdx.x * 32, nb = blockIdx.y * 32;
    const int tn = threadIdx.x & 31, tk = threadIdx.x >> 5;
#pragma unroll
    for (int i = 0; i < 4; ++i) {
        int k = tk + i * 8;
        tile[k][tn] = W[(size_t)(kb + k) * Ndim + nb + tn];
    }
    __syncthreads();
#pragma unroll
    for (int i = 0; i < 4; ++i) {
        int n = tk + i * 8;
        Wt[(size_t)(nb + n) * Kdim + kb + tn] = f2bf(tile[tn][n]);
    }
}

// ---------------------------------------------------------------------------
// LN1: x (2,64,64,1024) fp32 -> windowed bf16 (50*196, 1024); pad tokens = 0.
// ---------------------------------------------------------------------------
__global__ __launch_bounds__(256) void ln1_kernel(
    const float* __restrict__ x, const float* __restrict__ g,
    const float* __restrict__ b, unsigned short* __restrict__ out)
{
    const int blk = blockIdx.x;             // 0..9799
    const int tid = threadIdx.x;
    const int bw = blk / 196, tok = blk - bw * 196;
    const int bat = bw / 25, rw = bw - bat * 25;
    const int wy = rw / 5, wx = rw - wy * 5;
    const int ty = tok / 14, tx = tok - ty * 14;
    const int y = wy * 14 + ty, xx = wx * 14 + tx;
    unsigned short* orow = out + (size_t)blk * 1024;
    if (y >= 64 || xx >= 64) {
        *(uint2*)(orow + tid * 4) = make_uint2(0u, 0u);
        return;
    }
    const float* irow = x + ((size_t)((bat * 64 + y) * 64 + xx)) * 1024;
    const float4 v = *(const float4*)(irow + tid * 4);
    float s = v.x + v.y + v.z + v.w;
    float ss = v.x * v.x + v.y * v.y + v.z * v.z + v.w * v.w;
    for (int o = 32; o > 0; o >>= 1) { s += __shfl_xor(s, o); ss += __shfl_xor(ss, o); }
    __shared__ float red[8];
    const int wave = tid >> 6, lane = tid & 63;
    if (lane == 0) { red[wave] = s; red[4 + wave] = ss; }
    __syncthreads();
    s = red[0] + red[1] + red[2] + red[3];
    ss = red[4] + red[5] + red[6] + red[7];
    const float mu = s * (1.0f / 1024.0f);
    const float var = ss * (1.0f / 1024.0f) - mu * mu;
    const float rstd = rsqrtf(var + 1e-6f);
    const float4 gv = *(const float4*)(g + tid * 4);
    const float4 bv = *(const float4*)(b + tid * 4);
    const float a0 = (v.x - mu) * rstd * gv.x + bv.x;
    const float a1 = (v.y - mu) * rstd * gv.y + bv.y;
    const float a2 = (v.z - mu) * rstd * gv.z + bv.z;
    const float a3 = (v.w - mu) * rstd * gv.w + bv.w;
    const unsigned r0 = (unsigned)f2bf(a0) | ((unsigned)f2bf(a1) << 16);
    const unsigned r1 = (unsigned)f2bf(a2) | ((unsigned)f2bf(a3) << 16);
    *(uint2*)(orow + tid * 4) = make_uint2(r0, r1);
}

// LN2: rows of x1 (d_out, fp32) -> bf16, 8192 rows
__global__ __launch_bounds__(256) void ln2_kernel(
    const float* __restrict__ x, const float* __restrict__ g,
    const float* __restrict__ b, unsigned short* __restrict__ out)
{
    const int blk = blockIdx.x;
    const int tid = threadIdx.x;
    const float* irow = x + (size_t)blk * 1024;
    unsigned short* orow = out + (size_t)blk * 1024;
    const float4 v = *(const float4*)(irow + tid * 4);
    float s = v.x + v.y + v.z + v.w;
    float ss = v.x * v.x + v.y * v.y + v.z * v.z + v.w * v.w;
    for (int o = 32; o > 0; o >>= 1) { s += __shfl_xor(s, o); ss += __shfl_xor(ss, o); }
    __shared__ float red[8];
    const int wave = tid >> 6, lane = tid & 63;
    if (lane == 0) { red[wave] = s; red[4 + wave] = ss; }
    __syncthreads();
    s = red[0] + red[1] + red[2] + red[3];
    ss = red[4] + red[5] + red[6] + red[7];
    const float mu = s * (1.0f / 1024.0f);
    const float var = ss * (1.0f / 1024.0f) - mu * mu;
    const float rstd = rsqrtf(var + 1e-6f);
    const float4 gv = *(const float4*)(g + tid * 4);
    const float4 bv = *(const float4*)(b + tid * 4);
    const float a0 = (v.x - mu) * rstd * gv.x + bv.x;
    const float a1 = (v.y - mu) * rstd * gv.y + bv.y;
    const float a2 = (v.z - mu) * rstd * gv.z + bv.z;
    const float a3 = (v.w - mu) * rstd * gv.w + bv.w;
    const unsigned r0 = (unsigned)f2bf(a0) | ((unsigned)f2bf(a1) << 16);
    const unsigned r1 = (unsigned)f2bf(a2) | ((unsigned)f2bf(a3) << 16);
    *(uint2*)(orow + tid * 4) = make_uint2(r0, r1);
}

// ---------------------------------------------------------------------------
// GEMM: C[m][n] = sum_k A[m][k] * Bt[n][k]  (A: MxK bf16, Bt: NxK bf16)
// BK=64 (two XOR-swizzled 128x32 sub-tiles per barrier), band-swizzled grid,
// non-temporal epilogue stores (keep A/B L2-resident).
// LDS chunk swizzle: slot s holds k-chunk (s&3)^((row>>1)&3); fragment reads
// use swz = lq ^ ((lr>>1)&3) -> 2-way bank aliasing (free).
// ---------------------------------------------------------------------------
template <int EPI>
__global__ __launch_bounds__(256) void gemm_kernel(
    const unsigned short* __restrict__ A,
    const unsigned short* __restrict__ Bt,
    const float* __restrict__ bias,
    void* __restrict__ outp,
    const float* __restrict__ aux,
    int M, int K, int nbm, int nbn)
{
    __shared__ unsigned short As[2][128 * 32];
    __shared__ unsigned short Bs[2][128 * 32];
    const int tid = threadIdx.x;
    const int wave = tid >> 6, lane = tid & 63;
    const int lr = lane & 15, lq = lane >> 4;
    // band swizzle: 8 n-tiles per band, m fastest within band
    const int bandsz = nbm * 8;
    const int g = blockIdx.x / bandsz;
    const int rr = blockIdx.x - g * bandsz;
    const int mt = rr % nbm;
    const int nt = g * 8 + rr / nbm;
    if (nt >= nbn) return;                 // defensive tripwire (never taken)
    const int m_base = mt * 128, n_base = nt * 128;
    const int wm = (wave >> 1) * 64, wn = (wave & 1) * 64;
    const int N = nbn * 128;

    // staging: slot c holds global k-chunk kc = (c&3)^((row>>1)&3)
    const int c0 = tid, c1 = tid + 256;
    const int row0 = c0 >> 2, row1 = c1 >> 2;
    const int kc = (tid & 3) ^ ((tid >> 3) & 3);   // same for c0 and c1
    int ar0 = m_base + row0; ar0 = ar0 < M ? ar0 : M - 1;
    int ar1 = m_base + row1; ar1 = ar1 < M ? ar1 : M - 1;
    int br0 = n_base + row0; br0 = br0 < N ? br0 : N - 1;
    int br1 = n_base + row1; br1 = br1 < N ? br1 : N - 1;
    const unsigned short* agp0 = A + (size_t)ar0 * K + kc * 8;
    const unsigned short* agp1 = A + (size_t)ar1 * K + kc * 8;
    const unsigned short* bgp0 = Bt + (size_t)br0 * K + kc * 8;
    const unsigned short* bgp1 = Bt + (size_t)br1 * K + kc * 8;
    unsigned short* alp0 = As[0] + c0 * 8;
    unsigned short* alp1 = As[0] + c1 * 8;
    unsigned short* blp0 = Bs[0] + c0 * 8;
    unsigned short* blp1 = Bs[0] + c1 * 8;
    unsigned short* alp0b = As[1] + c0 * 8;
    unsigned short* alp1b = As[1] + c1 * 8;
    unsigned short* blp0b = Bs[1] + c0 * 8;
    unsigned short* blp1b = Bs[1] + c1 * 8;

    const int swz = (lq ^ ((lr >> 1) & 3)) * 8;    // fragment-read k-chunk offset

    f32x4 acc[4][4] = {};

    for (int k0 = 0; k0 < K; k0 += 64) {
        GLDS16(agp0 + k0, alp0);
        GLDS16(agp1 + k0, alp1);
        GLDS16(bgp0 + k0, blp0);
        GLDS16(bgp1 + k0, blp1);
        GLDS16(agp0 + k0 + 32, alp0b);
        GLDS16(agp1 + k0 + 32, alp1b);
        GLDS16(bgp0 + k0 + 32, blp0b);
        GLDS16(bgp1 + k0 + 32, blp1b);
        __syncthreads();
#pragma unroll
        for (int half = 0; half < 2; ++half) {
            bf16x8 af[4], bfr[4];
#pragma unroll
            for (int i = 0; i < 4; ++i) {
                af[i]  = *(const bf16x8*)(As[half] + (wm + i * 16 + lr) * 32 + swz);
                bfr[i] = *(const bf16x8*)(Bs[half] + (wn + i * 16 + lr) * 32 + swz);
            }
#pragma unroll
            for (int i = 0; i < 4; ++i)
#pragma unroll
                for (int j = 0; j < 4; ++j)
                    acc[i][j] = __builtin_amdgcn_mfma_f32_16x16x32_bf16(af[i], bfr[j], acc[i][j], 0, 0, 0);
        }
        __syncthreads();
    }

    float biasv[4];
#pragma unroll
    for (int j = 0; j < 4; ++j) biasv[j] = bias[n_base + wn + j * 16 + lr];

    if constexpr (EPI == 0) {
        // qkv scatter; V written transposed, packed 4 tokens (8B) per store.
        // 196 % 4 == 0 and M % 4 == 0 -> a 4-row chunk never straddles windows.
#pragma unroll
        for (int i = 0; i < 4; ++i) {
            const int m0i = m_base + wm + i * 16 + lq * 4;
            if (m0i >= M) continue;
            const int bw = m0i / 196, tok0 = m0i - bw * 196;
#pragma unroll
            for (int j = 0; j < 4; ++j) {
                const int n = n_base + wn + j * 16 + lr;
                const int which = n >> 10, hh = (n >> 6) & 15, d = n & 63;
                unsigned short* slotp = (unsigned short*)outp + (size_t)((bw * 3 + which) * 16 + hh) * 13312;
                if (which == 2) {
                    unsigned long long pv = 0;
#pragma unroll
                    for (int r = 0; r < 4; ++r)
                        pv |= (unsigned long long)f2bf(acc[i][j][r] + biasv[j]) << (16 * r);
                    __builtin_nontemporal_store(pv, (unsigned long long*)(slotp + (size_t)d * 208 + tok0));
                } else {
#pragma unroll
                    for (int r = 0; r < 4; ++r)
                        __builtin_nontemporal_store(f2bf(acc[i][j][r] + biasv[j]),
                                                    slotp + (size_t)(tok0 + r) * 64 + d);
                }
            }
        }
    } else {
#pragma unroll
        for (int i = 0; i < 4; ++i) {
#pragma unroll
            for (int r = 0; r < 4; ++r) {
                const int m = m_base + wm + i * 16 + lq * 4 + r;
                if (m >= M) continue;
                int y = 0, xx = 0, b = 0;
                if constexpr (EPI == 1) {
                    const int bw = m / 196, tok = m - bw * 196;
                    b = bw / 25;
                    const int rw = bw - b * 25;
                    const int wy = rw / 5, wx = rw - wy * 5;
                    const int ty = tok / 14, tx = tok - ty * 14;
                    y = wy * 14 + ty; xx = wx * 14 + tx;
                }
#pragma unroll
                for (int j = 0; j < 4; ++j) {
                    const int n = n_base + wn + j * 16 + lr;
                    const float v = acc[i][j][r] + biasv[j];
                    if constexpr (EPI == 1) {
                        if (y < 64 && xx < 64) {
                            const size_t idx = ((size_t)((b * 64 + y) * 64 + xx)) * 1024 + n;
                            __builtin_nontemporal_store(__builtin_nontemporal_load(&aux[idx]) + v,
                                                        &((float*)outp)[idx]);
                        }
                    } else if constexpr (EPI == 2) {
                        // fast tanh-GELU
                        const float t2 = 1.5957691216f * (v + 0.044715f * v * v * v);
                        const float e = __expf(-t2);
                        const float gl = v * __builtin_amdgcn_rcpf(1.0f + e);
                        __builtin_nontemporal_store(f2bf(gl), (unsigned short*)outp + (size_t)m * 4096 + n);
                    } else {
                        float* p = &((float*)outp)[(size_t)m * 1024 + n];
                        __builtin_nontemporal_store(*p + v, p);
                    }
                }
            }
        }
    }
}

// ---------------------------------------------------------------------------
// Windowed attention v2. Grid = 800 (window*head), 256 threads / 4 waves,
// 2 blocks/CU (LDS 70.4 KB, __launch_bounds__(256,2)).
// ---------------------------------------------------------------------------
__global__ __launch_bounds__(256, 2) void attn_kernel(
    const unsigned short* __restrict__ qkv,
    const float* __restrict__ relh, const float* __restrict__ relw,
    unsigned short* __restrict__ attn_out)
{
    __shared__ unsigned short Vt[64][232];     // V^T staged (cols 0..231 from global)
    __shared__ unsigned short Pst[4][16][232]; // per-wave P strip (A-layout via LDS)
    __shared__ unsigned short Db[196][28];     // rel bias: [m][0..13]=h, [14..27]=w

    const int tid = threadIdx.x;
    const int wave = tid >> 6, lane = tid & 63;
    const int lr = lane & 15, lq = lane >> 4;
    const int bw = blockIdx.x >> 4, h = blockIdx.x & 15;
    const unsigned short* qp = qkv + (size_t)((bw * 3 + 0) * 16 + h) * 13312;
    const unsigned short* kp = qkv + (size_t)((bw * 3 + 1) * 16 + h) * 13312;
    const unsigned short* vp = qkv + (size_t)((bw * 3 + 2) * 16 + h) * 13312;

    // zero this wave's Pst pad cols [208,224) once (never overwritten later)
    *(uint2*)&Pst[wave][lane >> 2][208 + (lane & 3) * 4] = make_uint2(0u, 0u);

    // stage V^T: 64 rows x 232 cols (29 x 16B chunks per row) async from global
    {
        unsigned short* vtf = &Vt[0][0];
        for (int idx = tid; idx < 64 * 29; idx += 256) {
            const int d = idx / 29, c = idx - d * 29;
            GLDS16(vp + d * 208 + c * 8, vtf + idx * 8);
        }
    }

    // rel-pos bias via MFMA: 28 tasks = (h:14 coords, w:14 coords)
    for (int t = wave; t < 28; t += 4) {
        const int isw = t >= 14;
        const int c = isw ? t - 14 : t;
        const int arow = isw ? (lr * 14 + c) : (c * 14 + lr);
        const unsigned short* ap = qp + arow * 64 + lq * 8;
        const bf16x8 a0 = *(const bf16x8*)ap;
        const bf16x8 a1 = *(const bf16x8*)(ap + 32);
        int ridx = c - lr + 13;
        ridx = ridx < 0 ? 0 : (ridx > 26 ? 26 : ridx);
        const float* tb = (isw ? relw : relh) + ridx * 64 + lq * 8;
        union BV { unsigned short u[8]; bf16x8 v; } b0, b1;
        {
            const float4 x0 = *(const float4*)tb;
            const float4 x1 = *(const float4*)(tb + 4);
            b0.u[0] = f2bf(x0.x); b0.u[1] = f2bf(x0.y); b0.u[2] = f2bf(x0.z); b0.u[3] = f2bf(x0.w);
            b0.u[4] = f2bf(x1.x); b0.u[5] = f2bf(x1.y); b0.u[6] = f2bf(x1.z); b0.u[7] = f2bf(x1.w);
            const float4 x2 = *(const float4*)(tb + 32);
            const float4 x3 = *(const float4*)(tb + 36);
            b1.u[0] = f2bf(x2.x); b1.u[1] = f2bf(x2.y); b1.u[2] = f2bf(x2.z); b1.u[3] = f2bf(x2.w);
            b1.u[4] = f2bf(x3.x); b1.u[5] = f2bf(x3.y); b1.u[6] = f2bf(x3.z); b1.u[7] = f2bf(x3.w);
        }
        f32x4 dacc = {};
        dacc = __builtin_amdgcn_mfma_f32_16x16x32_bf16(a0, b0.v, dacc, 0, 0, 0);
        dacc = __builtin_amdgcn_mfma_f32_16x16x32_bf16(a1, b1.v, dacc, 0, 0, 0);
#pragma unroll
        for (int r = 0; r < 4; ++r) {
            const int y = lq * 4 + r;
            if (y < 14 && lr < 14) {
                const int g = isw ? y * 14 + c : c * 14 + y;
                Db[g][isw ? 14 + lr : lr] = f2bf(dacc[r]);
            }
        }
    }
    __syncthreads();

    for (int mt = wave; mt < 13; mt += 4) {
        const int m0 = mt * 16;
        const unsigned short* qb = qp + (size_t)(m0 + lr) * 64 + lq * 8;
        const bf16x8 qa0 = *(const bf16x8*)qb;
        const bf16x8 qa1 = *(const bf16x8*)(qb + 32);
        f32x4 sc[13];
#pragma unroll
        for (int nt = 0; nt < 13; ++nt) {
            const unsigned short* kb = kp + (size_t)(nt * 16 + lr) * 64 + lq * 8;
            const bf16x8 k0 = *(const bf16x8*)kb;
            const bf16x8 k1 = *(const bf16x8*)(kb + 32);
            f32x4 a = {};
            a = __builtin_amdgcn_mfma_f32_16x16x32_bf16(qa0, k0, a, 0, 0, 0);
            a = __builtin_amdgcn_mfma_f32_16x16x32_bf16(qa1, k1, a, 0, 0, 0);
            sc[nt] = a;
        }
        int grow[4];
#pragma unroll
        for (int r = 0; r < 4; ++r) {
            int g = m0 + lq * 4 + r;
            grow[r] = g > 195 ? 195 : g;
        }
#pragma unroll
        for (int nt = 0; nt < 13; ++nt) {
            const int n = nt * 16 + lr;
            if (n < 196) {
                const int nx = n / 14, ny = n - nx * 14;
#pragma unroll
                for (int r = 0; r < 4; ++r)
                    sc[nt][r] = sc[nt][r] * 0.125f + bf2f(Db[grow[r]][nx]) + bf2f(Db[grow[r]][14 + ny]);
            } else {
#pragma unroll
                for (int r = 0; r < 4; ++r) sc[nt][r] = -1e30f;
            }
        }
        float rs[4];
#pragma unroll
        for (int r = 0; r < 4; ++r) {
            float mx = sc[0][r];
#pragma unroll
            for (int nt = 1; nt < 13; ++nt) mx = fmaxf(mx, sc[nt][r]);
            mx = fmaxf(mx, __shfl_xor(mx, 1));
            mx = fmaxf(mx, __shfl_xor(mx, 2));
            mx = fmaxf(mx, __shfl_xor(mx, 4));
            mx = fmaxf(mx, __shfl_xor(mx, 8));
            float s = 0.f;
#pragma unroll
            for (int nt = 0; nt < 13; ++nt) {
                const float e = __expf(sc[nt][r] - mx);
                sc[nt][r] = e;
                s += e;
            }
            s += __shfl_xor(s, 1);
            s += __shfl_xor(s, 2);
            s += __shfl_xor(s, 4);
            s += __shfl_xor(s, 8);
            rs[r] = 1.0f / s;
        }
#pragma unroll
        for (int nt = 0; nt < 13; ++nt)
#pragma unroll
            for (int r = 0; r < 4; ++r)
                Pst[wave][lq * 4 + r][nt * 16 + lr] = f2bf(sc[nt][r]);
#pragma unroll
        for (int dt = 0; dt < 4; ++dt) {
            f32x4 a = {};
#pragma unroll
            for (int ks = 0; ks < 7; ++ks) {
                const bf16x8 pa = *(const bf16x8*)&Pst[wave][lr][ks * 32 + lq * 8];
                const bf16x8 vb = *(const bf16x8*)&Vt[dt * 16 + lr][ks * 32 + lq * 8];
                a = __builtin_amdgcn_mfma_f32_16x16x32_bf16(pa, vb, a, 0, 0, 0);
            }
#pragma unroll
            for (int r = 0; r < 4; ++r) {
                const int m = m0 + lq * 4 + r;
                if (m < 196)
                    __builtin_nontemporal_store(f2bf(a[r] * rs[r]),
                        attn_out + (size_t)(bw * 196 + m) * 1024 + h * 64 + dt * 16 + lr);
            }
        }
    }
}

// ---------------------------------------------------------------------------
extern "C" void kernel_launch(void* const* d_in, const int* in_sizes, int n_in,
                              void* d_out, int out_size, void* d_ws, size_t ws_size,
                              hipStream_t stream)
{
    (void)in_sizes; (void)n_in; (void)out_size; (void)ws_size;
    const float* x      = (const float*)d_in[0];
    const float* n1g    = (const float*)d_in[1];
    const float* n1b    = (const float*)d_in[2];
    const float* qkv_w  = (const float*)d_in[3];
    const float* qkv_b  = (const float*)d_in[4];
    const float* lora_a = (const float*)d_in[5];
    const float* lora_b = (const float*)d_in[6];
    const float* relh   = (const float*)d_in[7];
    const float* relw   = (const float*)d_in[8];
    const float* proj_w = (const float*)d_in[9];
    const float* proj_b = (const float*)d_in[10];
    const float* n2g    = (const float*)d_in[11];
    const float* n2b    = (const float*)d_in[12];
    const float* w1     = (const float*)d_in[13];
    const float* b1     = (const float*)d_in[14];
    const float* w2     = (const float*)d_in[15];
    const float* b2     = (const float*)d_in[16];
    float* out = (float*)d_out;

    char* ws = (char*)d_ws;
    size_t off = 0;
    auto alloc = [&](size_t bytes) {
        char* p = ws + off;
        off += (bytes + 255) & ~(size_t)255;
        return p;
    };
    unsigned short* weffT = (unsigned short*)alloc((size_t)3072 * 1024 * 2);
    unsigned short* projT = (unsigned short*)alloc((size_t)1024 * 1024 * 2);
    unsigned short* w1T   = (unsigned short*)alloc((size_t)4096 * 1024 * 2);
    unsigned short* w2T   = (unsigned short*)alloc((size_t)1024 * 4096 * 2);
    unsigned short* xnw   = (unsigned short*)alloc((size_t)9800 * 1024 * 2); // later reused as xn2
    unsigned short* qkvb  = (unsigned short*)alloc((size_t)8192 * 4096 * 2); // qkv slots / later hmid
    unsigned short* attno = (unsigned short*)alloc((size_t)9800 * 1024 * 2);

    // weight prep (bf16, transposed to NxK)
    weff_kernel<<<dim3(32, 96), 256, 0, stream>>>(qkv_w, lora_a, lora_b, weffT);
    transpose_bf16_kernel<<<dim3(32, 32), 256, 0, stream>>>(proj_w, projT, 1024, 1024);
    transpose_bf16_kernel<<<dim3(32, 128), 256, 0, stream>>>(w1, w1T, 1024, 4096);
    transpose_bf16_kernel<<<dim3(128, 32), 256, 0, stream>>>(w2, w2T, 4096, 1024);
    // LN1 into windowed bf16 layout (pad tokens zeroed)
    ln1_kernel<<<9800, 256, 0, stream>>>(x, n1g, n1b, xnw);
    // QKV (+LoRA folded), scatter to padded slots (V pre-transposed)
    gemm_kernel<0><<<77 * 24, 256, 0, stream>>>(xnw, weffT, qkv_b, qkvb, nullptr, 9800, 1024, 77, 24);
    // windowed attention
    attn_kernel<<<800, 256, 0, stream>>>(qkvb, relh, relw, attno);
    // proj + bias + residual + unpartition -> d_out holds x1
    gemm_kernel<1><<<77 * 8, 256, 0, stream>>>(attno, projT, proj_b, out, x, 9800, 1024, 77, 8);
    // LN2
    unsigned short* xn2 = xnw;
    ln2_kernel<<<8192, 256, 0, stream>>>(out, n2g, n2b, xn2);
    // MLP
    unsigned short* hmid = qkvb;
    gemm_kernel<2><<<64 * 32, 256, 0, stream>>>(xn2, w1T, b1, hmid, nullptr, 8192, 1024, 64, 32);
    gemm_kernel<3><<<64 * 8, 256, 0, stream>>>(hmid, w2T, b2, out, nullptr, 8192, 4096, 64, 8);
}

// Round 7
// 581.563 us; speedup vs baseline: 1.1073x; 1.1073x over previous
//
#include <hip/hip_runtime.h>
#include <cstdint>
#include <cstddef>

// ============================================================================
// ViT block: LN1 -> (QKV + LoRA) -> 14x14 windowed attention (decomposed
// rel-pos bias) -> proj + residual -> LN2 -> MLP (fast-tanh GELU) + residual.
// bf16 MFMA 16x16x32, fp32 acc, BK=64, XOR-swizzled LDS (0 bank conflicts),
// XCD-stripe block mapping: each XCD owns ss m-tiles (A-stripe L2-resident),
// sweeps n slowest (B streams, L3-shared). Regular (cached) epilogue stores.
// qkv buffer layout: slot(bw,which,h) stride 13312 elements.
//   Q,K: [tok(208 pad)][64]   V: [64][tok(208 pad)]  (pre-transposed)
// ============================================================================

typedef __bf16 bf16x8 __attribute__((ext_vector_type(8)));
typedef float f32x4 __attribute__((ext_vector_type(4)));

__device__ __forceinline__ unsigned short f2bf(float f) {
    unsigned u = __float_as_uint(f);
    u = (u + 0x7fffu + ((u >> 16) & 1u)) >> 16;
    return (unsigned short)u;
}
__device__ __forceinline__ float bf2f(unsigned short h) {
    return __uint_as_float(((unsigned)h) << 16);
}

// async global->LDS, 16B per lane. LDS layout must be uniform_base + lane*16.
#define GLDS16(gp, lp) __builtin_amdgcn_global_load_lds( \
    (__attribute__((address_space(1))) unsigned int*)(gp), \
    (__attribute__((address_space(3))) unsigned int*)(lp), 16, 0, 0)

// ---------------------------------------------------------------------------
// Weight prep: W_effT[n][k] = qkv_w[k][n] + 2 * sum_r lora_a[k][r]*lora_b[r][n]
// ---------------------------------------------------------------------------
__global__ __launch_bounds__(256) void weff_kernel(
    const float* __restrict__ W, const float* __restrict__ la,
    const float* __restrict__ lb, unsigned short* __restrict__ Wt)
{
    __shared__ float tile[32][33];
    __shared__ float lat[32][16];
    __shared__ float lbt[16][32];
    const int kb = blockIdx.x * 32, nb = blockIdx.y * 32;
    const int tn = threadIdx.x & 31, tk = threadIdx.x >> 5;
    for (int i = threadIdx.x; i < 32 * 16; i += 256)
        lat[i >> 4][i & 15] = la[(size_t)(kb + (i >> 4)) * 16 + (i & 15)];
    for (int i = threadIdx.x; i < 16 * 32; i += 256)
        lbt[i >> 5][i & 31] = lb[(size_t)(i >> 5) * 3072 + nb + (i & 31)];
#pragma unroll
    for (int i = 0; i < 4; ++i) {
        int k = tk + i * 8;
        tile[k][tn] = W[(size_t)(kb + k) * 3072 + nb + tn];
    }
    __syncthreads();
#pragma unroll
    for (int i = 0; i < 4; ++i) {
        int n = tk + i * 8;
        float acc = tile[tn][n];
#pragma unroll
        for (int r = 0; r < 16; ++r) acc += 2.0f * lat[tn][r] * lbt[r][n];
        Wt[(size_t)(nb + n) * 1024 + kb + tn] = f2bf(acc);
    }
}

// fp32 (K x N) -> bf16 transposed (N x K)
__global__ __launch_bounds__(256) void transpose_bf16_kernel(
    const float* __restrict__ W, unsigned short* __restrict__ Wt,
    int Kdim, int Ndim)
{
    __shared__ float tile[32][33];
    const int kb = blockIdx.x * 32, nb = blockIdx.y * 32;
    const int tn = threadIdx.x & 31, tk = threadIdx.x >> 5;
#pragma unroll
    for (int i = 0; i < 4; ++i) {
        int k = tk + i * 8;
        tile[k][tn] = W[(size_t)(kb + k) * Ndim + nb + tn];
    }
    __syncthreads();
#pragma unroll
    for (int i = 0; i < 4; ++i) {
        int n = tk + i * 8;
        Wt[(size_t)(nb + n) * Kdim + kb + tn] = f2bf(tile[tn][n]);
    }
}

// ---------------------------------------------------------------------------
// LN1: x (2,64,64,1024) fp32 -> windowed bf16 (50*196, 1024); pad tokens = 0.
// ---------------------------------------------------------------------------
__global__ __launch_bounds__(256) void ln1_kernel(
    const float* __restrict__ x, const float* __restrict__ g,
    const float* __restrict__ b, unsigned short* __restrict__ out)
{
    const int blk = blockIdx.x;             // 0..9799
    const int tid = threadIdx.x;
    const int bw = blk / 196, tok = blk - bw * 196;
    const int bat = bw / 25, rw = bw - bat * 25;
    const int wy = rw / 5, wx = rw - wy * 5;
    const int ty = tok / 14, tx = tok - ty * 14;
    const int y = wy * 14 + ty, xx = wx * 14 + tx;
    unsigned short* orow = out + (size_t)blk * 1024;
    if (y >= 64 || xx >= 64) {
        *(uint2*)(orow + tid * 4) = make_uint2(0u, 0u);
        return;
    }
    const float* irow = x + ((size_t)((bat * 64 + y) * 64 + xx)) * 1024;
    const float4 v = *(const float4*)(irow + tid * 4);
    float s = v.x + v.y + v.z + v.w;
    float ss = v.x * v.x + v.y * v.y + v.z * v.z + v.w * v.w;
    for (int o = 32; o > 0; o >>= 1) { s += __shfl_xor(s, o); ss += __shfl_xor(ss, o); }
    __shared__ float red[8];
    const int wave = tid >> 6, lane = tid & 63;
    if (lane == 0) { red[wave] = s; red[4 + wave] = ss; }
    __syncthreads();
    s = red[0] + red[1] + red[2] + red[3];
    ss = red[4] + red[5] + red[6] + red[7];
    const float mu = s * (1.0f / 1024.0f);
    const float var = ss * (1.0f / 1024.0f) - mu * mu;
    const float rstd = rsqrtf(var + 1e-6f);
    const float4 gv = *(const float4*)(g + tid * 4);
    const float4 bv = *(const float4*)(b + tid * 4);
    const float a0 = (v.x - mu) * rstd * gv.x + bv.x;
    const float a1 = (v.y - mu) * rstd * gv.y + bv.y;
    const float a2 = (v.z - mu) * rstd * gv.z + bv.z;
    const float a3 = (v.w - mu) * rstd * gv.w + bv.w;
    const unsigned r0 = (unsigned)f2bf(a0) | ((unsigned)f2bf(a1) << 16);
    const unsigned r1 = (unsigned)f2bf(a2) | ((unsigned)f2bf(a3) << 16);
    *(uint2*)(orow + tid * 4) = make_uint2(r0, r1);
}

// LN2: rows of x1 (d_out, fp32) -> bf16, 8192 rows
__global__ __launch_bounds__(256) void ln2_kernel(
    const float* __restrict__ x, const float* __restrict__ g,
    const float* __restrict__ b, unsigned short* __restrict__ out)
{
    const int blk = blockIdx.x;
    const int tid = threadIdx.x;
    const float* irow = x + (size_t)blk * 1024;
    unsigned short* orow = out + (size_t)blk * 1024;
    const float4 v = *(const float4*)(irow + tid * 4);
    float s = v.x + v.y + v.z + v.w;
    float ss = v.x * v.x + v.y * v.y + v.z * v.z + v.w * v.w;
    for (int o = 32; o > 0; o >>= 1) { s += __shfl_xor(s, o); ss += __shfl_xor(ss, o); }
    __shared__ float red[8];
    const int wave = tid >> 6, lane = tid & 63;
    if (lane == 0) { red[wave] = s; red[4 + wave] = ss; }
    __syncthreads();
    s = red[0] + red[1] + red[2] + red[3];
    ss = red[4] + red[5] + red[6] + red[7];
    const float mu = s * (1.0f / 1024.0f);
    const float var = ss * (1.0f / 1024.0f) - mu * mu;
    const float rstd = rsqrtf(var + 1e-6f);
    const float4 gv = *(const float4*)(g + tid * 4);
    const float4 bv = *(const float4*)(b + tid * 4);
    const float a0 = (v.x - mu) * rstd * gv.x + bv.x;
    const float a1 = (v.y - mu) * rstd * gv.y + bv.y;
    const float a2 = (v.z - mu) * rstd * gv.z + bv.z;
    const float a3 = (v.w - mu) * rstd * gv.w + bv.w;
    const unsigned r0 = (unsigned)f2bf(a0) | ((unsigned)f2bf(a1) << 16);
    const unsigned r1 = (unsigned)f2bf(a2) | ((unsigned)f2bf(a3) << 16);
    *(uint2*)(orow + tid * 4) = make_uint2(r0, r1);
}

// ---------------------------------------------------------------------------
// GEMM: C[m][n] = sum_k A[m][k] * Bt[n][k]  (A: MxK bf16, Bt: NxK bf16)
// BK=64 (two XOR-swizzled 128x32 sub-tiles per barrier).
// XCD-stripe mapping: xcd = bid&7 owns m-tiles [xcd*ss, xcd*ss+ss); n slowest.
// A-stripe (~2.5 MB) stays L2-resident per XCD; B streams tile-by-tile.
// LDS chunk swizzle: slot s holds k-chunk (s&3)^((row>>1)&3); fragment reads
// use swz = lq ^ ((lr>>1)&3) -> 2-way bank aliasing (free).
// ---------------------------------------------------------------------------
template <int EPI>
__global__ __launch_bounds__(256) void gemm_kernel(
    const unsigned short* __restrict__ A,
    const unsigned short* __restrict__ Bt,
    const float* __restrict__ bias,
    void* __restrict__ outp,
    const float* __restrict__ aux,
    int M, int K, int nbm, int nbn)
{
    __shared__ unsigned short As[2][128 * 32];
    __shared__ unsigned short Bs[2][128 * 32];
    const int tid = threadIdx.x;
    const int wave = tid >> 6, lane = tid & 63;
    const int lr = lane & 15, lq = lane >> 4;
    // XCD-stripe mapping (perf heuristic: consecutive blocks round-robin XCDs)
    const int ss = (nbm + 7) >> 3;
    const int xcd = blockIdx.x & 7;
    const int s = blockIdx.x >> 3;
    const int nt = s / ss;
    const int m_loc = s - nt * ss;
    const int mt = xcd * ss + m_loc;
    if (mt >= nbm) return;
    const int m_base = mt * 128, n_base = nt * 128;
    const int wm = (wave >> 1) * 64, wn = (wave & 1) * 64;
    const int N = nbn * 128;

    // staging: slot c holds global k-chunk kc = (c&3)^((row>>1)&3)
    const int c0 = tid, c1 = tid + 256;
    const int row0 = c0 >> 2, row1 = c1 >> 2;
    const int kc = (tid & 3) ^ ((tid >> 3) & 3);   // same for c0 and c1
    int ar0 = m_base + row0; ar0 = ar0 < M ? ar0 : M - 1;
    int ar1 = m_base + row1; ar1 = ar1 < M ? ar1 : M - 1;
    int br0 = n_base + row0; br0 = br0 < N ? br0 : N - 1;
    int br1 = n_base + row1; br1 = br1 < N ? br1 : N - 1;
    const unsigned short* agp0 = A + (size_t)ar0 * K + kc * 8;
    const unsigned short* agp1 = A + (size_t)ar1 * K + kc * 8;
    const unsigned short* bgp0 = Bt + (size_t)br0 * K + kc * 8;
    const unsigned short* bgp1 = Bt + (size_t)br1 * K + kc * 8;
    unsigned short* alp0 = As[0] + c0 * 8;
    unsigned short* alp1 = As[0] + c1 * 8;
    unsigned short* blp0 = Bs[0] + c0 * 8;
    unsigned short* blp1 = Bs[0] + c1 * 8;
    unsigned short* alp0b = As[1] + c0 * 8;
    unsigned short* alp1b = As[1] + c1 * 8;
    unsigned short* blp0b = Bs[1] + c0 * 8;
    unsigned short* blp1b = Bs[1] + c1 * 8;

    const int swz = (lq ^ ((lr >> 1) & 3)) * 8;    // fragment-read k-chunk offset

    f32x4 acc[4][4] = {};

    for (int k0 = 0; k0 < K; k0 += 64) {
        GLDS16(agp0 + k0, alp0);
        GLDS16(agp1 + k0, alp1);
        GLDS16(bgp0 + k0, blp0);
        GLDS16(bgp1 + k0, blp1);
        GLDS16(agp0 + k0 + 32, alp0b);
        GLDS16(agp1 + k0 + 32, alp1b);
        GLDS16(bgp0 + k0 + 32, blp0b);
        GLDS16(bgp1 + k0 + 32, blp1b);
        __syncthreads();
#pragma unroll
        for (int half = 0; half < 2; ++half) {
            bf16x8 af[4], bfr[4];
#pragma unroll
            for (int i = 0; i < 4; ++i) {
                af[i]  = *(const bf16x8*)(As[half] + (wm + i * 16 + lr) * 32 + swz);
                bfr[i] = *(const bf16x8*)(Bs[half] + (wn + i * 16 + lr) * 32 + swz);
            }
#pragma unroll
            for (int i = 0; i < 4; ++i)
#pragma unroll
                for (int j = 0; j < 4; ++j)
                    acc[i][j] = __builtin_amdgcn_mfma_f32_16x16x32_bf16(af[i], bfr[j], acc[i][j], 0, 0, 0);
        }
        __syncthreads();
    }

    float biasv[4];
#pragma unroll
    for (int j = 0; j < 4; ++j) biasv[j] = bias[n_base + wn + j * 16 + lr];

    if constexpr (EPI == 0) {
        // qkv scatter; V written transposed, packed 4 tokens (8B) per store.
        // 196 % 4 == 0 and M % 4 == 0 -> a 4-row chunk never straddles windows.
#pragma unroll
        for (int i = 0; i < 4; ++i) {
            const int m0i = m_base + wm + i * 16 + lq * 4;
            if (m0i >= M) continue;
            const int bw = m0i / 196, tok0 = m0i - bw * 196;
#pragma unroll
            for (int j = 0; j < 4; ++j) {
                const int n = n_base + wn + j * 16 + lr;
                const int which = n >> 10, hh = (n >> 6) & 15, d = n & 63;
                unsigned short* slotp = (unsigned short*)outp + (size_t)((bw * 3 + which) * 16 + hh) * 13312;
                if (which == 2) {
                    unsigned long long pv = 0;
#pragma unroll
                    for (int r = 0; r < 4; ++r)
                        pv |= (unsigned long long)f2bf(acc[i][j][r] + biasv[j]) << (16 * r);
                    *(unsigned long long*)(slotp + (size_t)d * 208 + tok0) = pv;
                } else {
#pragma unroll
                    for (int r = 0; r < 4; ++r)
                        slotp[(size_t)(tok0 + r) * 64 + d] = f2bf(acc[i][j][r] + biasv[j]);
                }
            }
        }
    } else {
#pragma unroll
        for (int i = 0; i < 4; ++i) {
#pragma unroll
            for (int r = 0; r < 4; ++r) {
                const int m = m_base + wm + i * 16 + lq * 4 + r;
                if (m >= M) continue;
                int y = 0, xx = 0, b = 0;
                if constexpr (EPI == 1) {
                    const int bw = m / 196, tok = m - bw * 196;
                    b = bw / 25;
                    const int rw = bw - b * 25;
                    const int wy = rw / 5, wx = rw - wy * 5;
                    const int ty = tok / 14, tx = tok - ty * 14;
                    y = wy * 14 + ty; xx = wx * 14 + tx;
                }
#pragma unroll
                for (int j = 0; j < 4; ++j) {
                    const int n = n_base + wn + j * 16 + lr;
                    const float v = acc[i][j][r] + biasv[j];
                    if constexpr (EPI == 1) {
                        if (y < 64 && xx < 64) {
                            const size_t idx = ((size_t)((b * 64 + y) * 64 + xx)) * 1024 + n;
                            ((float*)outp)[idx] = aux[idx] + v;
                        }
                    } else if constexpr (EPI == 2) {
                        // fast tanh-GELU
                        const float t2 = 1.5957691216f * (v + 0.044715f * v * v * v);
                        const float e = __expf(-t2);
                        const float gl = v * __builtin_amdgcn_rcpf(1.0f + e);
                        ((unsigned short*)outp)[(size_t)m * 4096 + n] = f2bf(gl);
                    } else {
                        const size_t idx = (size_t)m * 1024 + n;
                        ((float*)outp)[idx] += v;
                    }
                }
            }
        }
    }
}

// ---------------------------------------------------------------------------
// Windowed attention v2. Grid = 800 (window*head), 256 threads / 4 waves,
// 2 blocks/CU (LDS 70.4 KB, __launch_bounds__(256,2)).
// ---------------------------------------------------------------------------
__global__ __launch_bounds__(256, 2) void attn_kernel(
    const unsigned short* __restrict__ qkv,
    const float* __restrict__ relh, const float* __restrict__ relw,
    unsigned short* __restrict__ attn_out)
{
    __shared__ unsigned short Vt[64][232];     // V^T staged (cols 0..231 from global)
    __shared__ unsigned short Pst[4][16][232]; // per-wave P strip (A-layout via LDS)
    __shared__ unsigned short Db[196][28];     // rel bias: [m][0..13]=h, [14..27]=w

    const int tid = threadIdx.x;
    const int wave = tid >> 6, lane = tid & 63;
    const int lr = lane & 15, lq = lane >> 4;
    const int bw = blockIdx.x >> 4, h = blockIdx.x & 15;
    const unsigned short* qp = qkv + (size_t)((bw * 3 + 0) * 16 + h) * 13312;
    const unsigned short* kp = qkv + (size_t)((bw * 3 + 1) * 16 + h) * 13312;
    const unsigned short* vp = qkv + (size_t)((bw * 3 + 2) * 16 + h) * 13312;

    // zero this wave's Pst pad cols [208,224) once (never overwritten later)
    *(uint2*)&Pst[wave][lane >> 2][208 + (lane & 3) * 4] = make_uint2(0u, 0u);

    // stage V^T: 64 rows x 232 cols (29 x 16B chunks per row) async from global
    {
        unsigned short* vtf = &Vt[0][0];
        for (int idx = tid; idx < 64 * 29; idx += 256) {
            const int d = idx / 29, c = idx - d * 29;
            GLDS16(vp + d * 208 + c * 8, vtf + idx * 8);
        }
    }

    // rel-pos bias via MFMA: 28 tasks = (h:14 coords, w:14 coords)
    for (int t = wave; t < 28; t += 4) {
        const int isw = t >= 14;
        const int c = isw ? t - 14 : t;
        const int arow = isw ? (lr * 14 + c) : (c * 14 + lr);
        const unsigned short* ap = qp + arow * 64 + lq * 8;
        const bf16x8 a0 = *(const bf16x8*)ap;
        const bf16x8 a1 = *(const bf16x8*)(ap + 32);
        int ridx = c - lr + 13;
        ridx = ridx < 0 ? 0 : (ridx > 26 ? 26 : ridx);
        const float* tb = (isw ? relw : relh) + ridx * 64 + lq * 8;
        union BV { unsigned short u[8]; bf16x8 v; } b0, b1;
        {
            const float4 x0 = *(const float4*)tb;
            const float4 x1 = *(const float4*)(tb + 4);
            b0.u[0] = f2bf(x0.x); b0.u[1] = f2bf(x0.y); b0.u[2] = f2bf(x0.z); b0.u[3] = f2bf(x0.w);
            b0.u[4] = f2bf(x1.x); b0.u[5] = f2bf(x1.y); b0.u[6] = f2bf(x1.z); b0.u[7] = f2bf(x1.w);
            const float4 x2 = *(const float4*)(tb + 32);
            const float4 x3 = *(const float4*)(tb + 36);
            b1.u[0] = f2bf(x2.x); b1.u[1] = f2bf(x2.y); b1.u[2] = f2bf(x2.z); b1.u[3] = f2bf(x2.w);
            b1.u[4] = f2bf(x3.x); b1.u[5] = f2bf(x3.y); b1.u[6] = f2bf(x3.z); b1.u[7] = f2bf(x3.w);
        }
        f32x4 dacc = {};
        dacc = __builtin_amdgcn_mfma_f32_16x16x32_bf16(a0, b0.v, dacc, 0, 0, 0);
        dacc = __builtin_amdgcn_mfma_f32_16x16x32_bf16(a1, b1.v, dacc, 0, 0, 0);
#pragma unroll
        for (int r = 0; r < 4; ++r) {
            const int y = lq * 4 + r;
            if (y < 14 && lr < 14) {
                const int g = isw ? y * 14 + c : c * 14 + y;
                Db[g][isw ? 14 + lr : lr] = f2bf(dacc[r]);
            }
        }
    }
    __syncthreads();

    for (int mt = wave; mt < 13; mt += 4) {
        const int m0 = mt * 16;
        const unsigned short* qb = qp + (size_t)(m0 + lr) * 64 + lq * 8;
        const bf16x8 qa0 = *(const bf16x8*)qb;
        const bf16x8 qa1 = *(const bf16x8*)(qb + 32);
        f32x4 sc[13];
#pragma unroll
        for (int nt = 0; nt < 13; ++nt) {
            const unsigned short* kb = kp + (size_t)(nt * 16 + lr) * 64 + lq * 8;
            const bf16x8 k0 = *(const bf16x8*)kb;
            const bf16x8 k1 = *(const bf16x8*)(kb + 32);
            f32x4 a = {};
            a = __builtin_amdgcn_mfma_f32_16x16x32_bf16(qa0, k0, a, 0, 0, 0);
            a = __builtin_amdgcn_mfma_f32_16x16x32_bf16(qa1, k1, a, 0, 0, 0);
            sc[nt] = a;
        }
        int grow[4];
#pragma unroll
        for (int r = 0; r < 4; ++r) {
            int g = m0 + lq * 4 + r;
            grow[r] = g > 195 ? 195 : g;
        }
#pragma unroll
        for (int nt = 0; nt < 13; ++nt) {
            const int n = nt * 16 + lr;
            if (n < 196) {
                const int nx = n / 14, ny = n - nx * 14;
#pragma unroll
                for (int r = 0; r < 4; ++r)
                    sc[nt][r] = sc[nt][r] * 0.125f + bf2f(Db[grow[r]][nx]) + bf2f(Db[grow[r]][14 + ny]);
            } else {
#pragma unroll
                for (int r = 0; r < 4; ++r) sc[nt][r] = -1e30f;
            }
        }
        float rs[4];
#pragma unroll
        for (int r = 0; r < 4; ++r) {
            float mx = sc[0][r];
#pragma unroll
            for (int nt = 1; nt < 13; ++nt) mx = fmaxf(mx, sc[nt][r]);
            mx = fmaxf(mx, __shfl_xor(mx, 1));
            mx = fmaxf(mx, __shfl_xor(mx, 2));
            mx = fmaxf(mx, __shfl_xor(mx, 4));
            mx = fmaxf(mx, __shfl_xor(mx, 8));
            float s = 0.f;
#pragma unroll
            for (int nt = 0; nt < 13; ++nt) {
                const float e = __expf(sc[nt][r] - mx);
                sc[nt][r] = e;
                s += e;
            }
            s += __shfl_xor(s, 1);
            s += __shfl_xor(s, 2);
            s += __shfl_xor(s, 4);
            s += __shfl_xor(s, 8);
            rs[r] = 1.0f / s;
        }
#pragma unroll
        for (int nt = 0; nt < 13; ++nt)
#pragma unroll
            for (int r = 0; r < 4; ++r)
                Pst[wave][lq * 4 + r][nt * 16 + lr] = f2bf(sc[nt][r]);
#pragma unroll
        for (int dt = 0; dt < 4; ++dt) {
            f32x4 a = {};
#pragma unroll
            for (int ks = 0; ks < 7; ++ks) {
                const bf16x8 pa = *(const bf16x8*)&Pst[wave][lr][ks * 32 + lq * 8];
                const bf16x8 vb = *(const bf16x8*)&Vt[dt * 16 + lr][ks * 32 + lq * 8];
                a = __builtin_amdgcn_mfma_f32_16x16x32_bf16(pa, vb, a, 0, 0, 0);
            }
#pragma unroll
            for (int r = 0; r < 4; ++r) {
                const int m = m0 + lq * 4 + r;
                if (m < 196)
                    attn_out[(size_t)(bw * 196 + m) * 1024 + h * 64 + dt * 16 + lr] = f2bf(a[r] * rs[r]);
            }
        }
    }
}

// ---------------------------------------------------------------------------
extern "C" void kernel_launch(void* const* d_in, const int* in_sizes, int n_in,
                              void* d_out, int out_size, void* d_ws, size_t ws_size,
                              hipStream_t stream)
{
    (void)in_sizes; (void)n_in; (void)out_size; (void)ws_size;
    const float* x      = (const float*)d_in[0];
    const float* n1g    = (const float*)d_in[1];
    const float* n1b    = (const float*)d_in[2];
    const float* qkv_w  = (const float*)d_in[3];
    const float* qkv_b  = (const float*)d_in[4];
    const float* lora_a = (const float*)d_in[5];
    const float* lora_b = (const float*)d_in[6];
    const float* relh   = (const float*)d_in[7];
    const float* relw   = (const float*)d_in[8];
    const float* proj_w = (const float*)d_in[9];
    const float* proj_b = (const float*)d_in[10];
    const float* n2g    = (const float*)d_in[11];
    const float* n2b    = (const float*)d_in[12];
    const float* w1     = (const float*)d_in[13];
    const float* b1     = (const float*)d_in[14];
    const float* w2     = (const float*)d_in[15];
    const float* b2     = (const float*)d_in[16];
    float* out = (float*)d_out;

    char* ws = (char*)d_ws;
    size_t off = 0;
    auto alloc = [&](size_t bytes) {
        char* p = ws + off;
        off += (bytes + 255) & ~(size_t)255;
        return p;
    };
    unsigned short* weffT = (unsigned short*)alloc((size_t)3072 * 1024 * 2);
    unsigned short* projT = (unsigned short*)alloc((size_t)1024 * 1024 * 2);
    unsigned short* w1T   = (unsigned short*)alloc((size_t)4096 * 1024 * 2);
    unsigned short* w2T   = (unsigned short*)alloc((size_t)1024 * 4096 * 2);
    unsigned short* xnw   = (unsigned short*)alloc((size_t)9800 * 1024 * 2); // later reused as xn2
    unsigned short* qkvb  = (unsigned short*)alloc((size_t)8192 * 4096 * 2); // qkv slots / later hmid
    unsigned short* attno = (unsigned short*)alloc((size_t)9800 * 1024 * 2);

    // weight prep (bf16, transposed to NxK)
    weff_kernel<<<dim3(32, 96), 256, 0, stream>>>(qkv_w, lora_a, lora_b, weffT);
    transpose_bf16_kernel<<<dim3(32, 32), 256, 0, stream>>>(proj_w, projT, 1024, 1024);
    transpose_bf16_kernel<<<dim3(32, 128), 256, 0, stream>>>(w1, w1T, 1024, 4096);
    transpose_bf16_kernel<<<dim3(128, 32), 256, 0, stream>>>(w2, w2T, 4096, 1024);
    // LN1 into windowed bf16 layout (pad tokens zeroed)
    ln1_kernel<<<9800, 256, 0, stream>>>(x, n1g, n1b, xnw);
    // QKV (+LoRA folded), scatter to padded slots (V pre-transposed)
    // grids: 8 XCD-stripes x ss x nbn, ss = ceil(nbm/8)
    gemm_kernel<0><<<8 * 10 * 24, 256, 0, stream>>>(xnw, weffT, qkv_b, qkvb, nullptr, 9800, 1024, 77, 24);
    // windowed attention
    attn_kernel<<<800, 256, 0, stream>>>(qkvb, relh, relw, attno);
    // proj + bias + residual + unpartition -> d_out holds x1
    gemm_kernel<1><<<8 * 10 * 8, 256, 0, stream>>>(attno, projT, proj_b, out, x, 9800, 1024, 77, 8);
    // LN2
    unsigned short* xn2 = xnw;
    ln2_kernel<<<8192, 256, 0, stream>>>(out, n2g, n2b, xn2);
    // MLP
    unsigned short* hmid = qkvb;
    gemm_kernel<2><<<8 * 8 * 32, 256, 0, stream>>>(xn2, w1T, b1, hmid, nullptr, 8192, 1024, 64, 32);
    gemm_kernel<3><<<8 * 8 * 8, 256, 0, stream>>>(hmid, w2T, b2, out, nullptr, 8192, 4096, 64, 8);
}